// Round 5
// baseline (1030.585 us; speedup 1.0000x reference)
//
#include <hip/hip_runtime.h>
#include <hip/hip_bf16.h>
#include <math.h>

// Problem constants (match reference)
#define RR 10
#define BB 8
#define NN 8192
#define HH 8
#define BN 65536            // BB*NN nodes per ROI
#define EE (1u << 20)       // directed edges per ROI = 2*B*EPAIR
#define EPB (EE / BB)       // 131072 directed edges per (ROI,patient), contiguous
#define KK 4096             // TopK ratio 0.5
#define NSUP 80             // B*R super nodes

#define NTL(p) __builtin_nontemporal_load(p)

// ---------------- pass 1: per-(r,b) in-degree via LDS histogram -> dis = rsqrt(deg+1) ----------------
// blockIdx == rb (idx%8 == b -> all work for patient b pinned to XCD b%8)
__global__ __launch_bounds__(1024)
void deg_dis_kernel(const int* __restrict__ ei, float* __restrict__ dis) {
  const int r = blockIdx.x / BB;
  const int b = blockIdx.x % BB;
  const int tid = threadIdx.x;
  __shared__ int cnt[NN];                     // 32 KB
  for (int n = tid; n < NN; n += 1024) cnt[n] = 0;
  __syncthreads();
  const int* dstp = ei + ((size_t)r * 2u + 1u) * EE + (size_t)b * EPB;
  // 4-edge ILP batches, nontemporal (stream; don't evict L2)
  for (int e0 = tid; e0 + 3072 < EPB; e0 += 4096) {
    int d0 = NTL(dstp + e0);
    int d1 = NTL(dstp + e0 + 1024);
    int d2 = NTL(dstp + e0 + 2048);
    int d3 = NTL(dstp + e0 + 3072);
    atomicAdd(&cnt[d0 & (NN - 1)], 1);
    atomicAdd(&cnt[d1 & (NN - 1)], 1);
    atomicAdd(&cnt[d2 & (NN - 1)], 1);
    atomicAdd(&cnt[d3 & (NN - 1)], 1);
  }
  __syncthreads();
  float* dp = dis + (size_t)r * BN + (size_t)b * NN;
  for (int n = tid; n < NN; n += 1024) dp[n] = rsqrtf((float)cnt[n] + 1.0f);
}

// ---------------- pass 2: per-(r,b,half,chunk) LDS-private scatter-add of 4 channels ----------------
// grid = 80 * 2 * nchunks; idx = inner*80 + rb  (80%8==0 -> idx%8 == b: XCD-pinned per patient)
__global__ __launch_bounds__(1024)
void agg_kernel2(const int* __restrict__ ei,
                 const float* __restrict__ x,
                 const float* __restrict__ gcn_w,
                 const float* __restrict__ dis,
                 float* __restrict__ aggp,      // [nchunks][RR*BN*8]
                 int nchunks) {
  const int rb = blockIdx.x % 80;
  const int inner = blockIdx.x / 80;           // 0..2*nchunks-1
  const int half = inner & 1;
  const int chunk = inner >> 1;
  const int r = rb / BB;
  const int b = rb % BB;
  const int tid = threadIdx.x;
  const int epc = EPB / nchunks;

  __shared__ float acc[NN * 4];                // 128 KB
  for (int i = tid; i < NN * 4; i += 1024) acc[i] = 0.f;

  // weight columns for channels [half*4, half*4+4): w4[in][c]
  float w4[4][4];
#pragma unroll
  for (int in = 0; in < 4; ++in)
#pragma unroll
    for (int c = 0; c < 4; ++c)
      w4[in][c] = gcn_w[r * 32 + in * 8 + half * 4 + c];
  __syncthreads();

  const int* base = ei + (size_t)r * 2u * EE;
  const int* srcp = base + (size_t)b * EPB + (size_t)chunk * epc;
  const int* dstp = base + EE + (size_t)b * EPB + (size_t)chunk * epc;
  const float* disr = dis + (size_t)r * BN;
  const float4* x4 = (const float4*)x + (size_t)r * BN;

  // 4-edge ILP batches: issue all index loads, then all gathers, then compute+atomics
  for (int e0 = tid; e0 + 3072 < epc; e0 += 4096) {
    int s0 = NTL(srcp + e0);
    int s1 = NTL(srcp + e0 + 1024);
    int s2 = NTL(srcp + e0 + 2048);
    int s3 = NTL(srcp + e0 + 3072);
    int d0 = NTL(dstp + e0);
    int d1 = NTL(dstp + e0 + 1024);
    int d2 = NTL(dstp + e0 + 2048);
    int d3 = NTL(dstp + e0 + 3072);
    float n0 = disr[s0] * disr[d0];
    float n1 = disr[s1] * disr[d1];
    float n2 = disr[s2] * disr[d2];
    float n3 = disr[s3] * disr[d3];
    float4 xv0 = x4[s0];
    float4 xv1 = x4[s1];
    float4 xv2 = x4[s2];
    float4 xv3 = x4[s3];
    int l0 = d0 & (NN - 1), l1 = d1 & (NN - 1), l2 = d2 & (NN - 1), l3 = d3 & (NN - 1);
#pragma unroll
    for (int c = 0; c < 4; ++c) {
      // channel-rotate swizzle: bank = node*4 + (c+node)%4 -> spreads random nodes over all 32 banks
      float h0 = xv0.x * w4[0][c] + xv0.y * w4[1][c] + xv0.z * w4[2][c] + xv0.w * w4[3][c];
      atomicAdd(&acc[(l0 << 2) | ((c + l0) & 3)], h0 * n0);
      float h1 = xv1.x * w4[0][c] + xv1.y * w4[1][c] + xv1.z * w4[2][c] + xv1.w * w4[3][c];
      atomicAdd(&acc[(l1 << 2) | ((c + l1) & 3)], h1 * n1);
      float h2 = xv2.x * w4[0][c] + xv2.y * w4[1][c] + xv2.z * w4[2][c] + xv2.w * w4[3][c];
      atomicAdd(&acc[(l2 << 2) | ((c + l2) & 3)], h2 * n2);
      float h3 = xv3.x * w4[0][c] + xv3.y * w4[1][c] + xv3.z * w4[2][c] + xv3.w * w4[3][c];
      atomicAdd(&acc[(l3 << 2) | ((c + l3) & 3)], h3 * n3);
    }
  }
  __syncthreads();

  // writeout (unswizzle): node n channels [half*4, half*4+4) as one float4
  float* ap = aggp + (size_t)chunk * ((size_t)RR * BN * 8)
            + ((size_t)r * BN + (size_t)b * NN) * 8 + half * 4;
  for (int n = tid; n < NN; n += 1024) {
    int nl = n << 2;
    float4 v;
    v.x = acc[nl | ((0 + n) & 3)];
    v.y = acc[nl | ((1 + n) & 3)];
    v.z = acc[nl | ((2 + n) & 3)];
    v.w = acc[nl | ((3 + n) & 3)];
    *(float4*)(ap + (size_t)n * 8) = v;
  }
}

// ---------------- per-(ROI,patient): combine + graph-LN + score + radix-select topK + pools ----------------
__global__ __launch_bounds__(1024)
void roi_kernel(const float* __restrict__ x,
                const float* __restrict__ gcn_w,
                const float* __restrict__ gcn_b,
                const float* __restrict__ ln_w,
                const float* __restrict__ ln_b,
                const float* __restrict__ topk_w,
                const float* __restrict__ cen,
                const float* __restrict__ dis,
                float* __restrict__ aggp,     // chunk0: agg in -> hrelu -> hn (in place); chunk1: partial
                float* __restrict__ feats,
                int nchunks) {
  const int r = blockIdx.x / BB;
  const int b = blockIdx.x % BB;
  const int tid = threadIdx.x;

  __shared__ double dred[1024];    // 8 KB reduction
  __shared__ int tscan[1024];      // tie prefix-scan
  __shared__ int hist[256];        // radix histogram
  __shared__ float chanSum[8];
  __shared__ float fvSum[8];
  __shared__ int cntGt;
  __shared__ int selb, kleft;

  if (tid < 8) { chanSum[tid] = 0.f; fvSum[tid] = 0.f; }
  if (tid == 0) cntGt = 0;

  float w[32], bg[8], lw[8], lb[8], wt[8];
#pragma unroll
  for (int i = 0; i < 32; ++i) w[i] = gcn_w[r * 32 + i];
  float wn2 = 0.f;
#pragma unroll
  for (int c = 0; c < 8; ++c) {
    bg[c] = gcn_b[r * 8 + c];
    lw[c] = ln_w[r * 8 + c];
    lb[c] = ln_b[r * 8 + c];
    wt[c] = topk_w[r * 8 + c];
    wn2 += wt[c] * wt[c];
  }
  const float invn = 1.0f / sqrtf(wn2);

  const float4* x4 = (const float4*)x + (size_t)r * BN + (size_t)b * NN;
  const float* disp = dis + (size_t)r * BN + (size_t)b * NN;
  float* hp = aggp + ((size_t)r * BN + (size_t)b * NN) * 8;
  const float* hp1 = hp + (size_t)RR * BN * 8;   // chunk-1 partial (if nchunks==2)

  // Pass A: hrelu = relu(sum(partials) + h_self/deg + bias); fp64 LN stats
  double s1 = 0.0, s2 = 0.0;
#pragma unroll
  for (int i = 0; i < 8; ++i) {
    int n = tid * 8 + i;
    float4 xv = x4[n];
    float ds = disp[n];
    float invd = ds * ds;          // = 1/(deg+1) up to rsqrt rounding
#pragma unroll
    for (int c = 0; c < 8; ++c) {
      float hs = xv.x * w[c] + xv.y * w[8 + c] + xv.z * w[16 + c] + xv.w * w[24 + c];
      float a = hp[n * 8 + c];
      if (nchunks == 2) a += hp1[n * 8 + c];
      float v = a + hs * invd + bg[c];
      v = fmaxf(v, 0.0f);
      hp[n * 8 + c] = v;
      s1 += v;
      s2 += (double)v * v;
    }
  }
  dred[tid] = s1;
  __syncthreads();
  for (int off = 512; off > 0; off >>= 1) {
    if (tid < off) dred[tid] += dred[tid + off];
    __syncthreads();
  }
  double tot1 = dred[0];
  __syncthreads();
  dred[tid] = s2;
  __syncthreads();
  for (int off = 512; off > 0; off >>= 1) {
    if (tid < off) dred[tid] += dred[tid + off];
    __syncthreads();
  }
  double tot2 = dred[0];
  const double M = (double)NN * HH;
  double mu = tot1 / M;
  double var = tot2 / M - mu * mu;
  float muf = (float)mu;
  float rstd = (float)(1.0 / sqrt(var + 1e-5));

  // Pass B: normalize (in place), per-channel sums (res), scores
  float ch[8] = {0, 0, 0, 0, 0, 0, 0, 0};
  float sv[8];
  unsigned fl[8];
#pragma unroll
  for (int i = 0; i < 8; ++i) {
    int n = tid * 8 + i;
    float pre = 0.f;
#pragma unroll
    for (int c = 0; c < 8; ++c) {
      float v = hp[n * 8 + c];
      float hn = (v - muf) * rstd * lw[c] + lb[c];
      hp[n * 8 + c] = hn;
      ch[c] += hn;
      pre += hn * wt[c];
    }
    float s = tanhf(pre * invn);
    sv[i] = s;
    unsigned u = __float_as_uint(s);
    fl[i] = (u & 0x80000000u) ? ~u : (u | 0x80000000u);  // monotonic flip
  }
#pragma unroll
  for (int c = 0; c < 8; ++c) atomicAdd(&chanSum[c], ch[c]);

  // Radix-select the K-th largest (exact 32-bit value), 4 passes of 8 bits
  unsigned prefix = 0;
  int kneed = KK;
  for (int shift = 24; shift >= 0; shift -= 8) {
    __syncthreads();
    if (tid < 256) hist[tid] = 0;
    __syncthreads();
#pragma unroll
    for (int i = 0; i < 8; ++i) {
      bool m = (shift == 24) || ((fl[i] >> (shift + 8)) == prefix);
      if (m) atomicAdd(&hist[(fl[i] >> shift) & 255], 1);
    }
    __syncthreads();
    if (tid == 0) {
      int kn = kneed, bsel = 0;
      for (int bb2 = 255; bb2 >= 0; --bb2) {
        int c = hist[bb2];
        if (kn - c <= 0) { bsel = bb2; break; }
        kn -= c;
      }
      selb = bsel; kleft = kn;
    }
    __syncthreads();
    prefix = (prefix << 8) | (unsigned)selb;
    kneed = kleft;
  }
  float tau = (prefix & 0x80000000u) ? __uint_as_float(prefix & 0x7fffffffu)
                                     : __uint_as_float(~prefix);

  // count strictly-greater; tie-break lowest-index-first (matches lax.top_k)
  int cg = 0, ct = 0;
#pragma unroll
  for (int i = 0; i < 8; ++i) {
    if (sv[i] > tau) cg++;
    else if (sv[i] == tau) ct++;
  }
  atomicAdd(&cntGt, cg);
  tscan[tid] = ct;
  __syncthreads();
  if (tid == 0) {
    int run = 0;
    for (int t = 0; t < 1024; ++t) { int tmp = tscan[t]; tscan[t] = run; run += tmp; }
  }
  __syncthreads();
  int quota = KK - cntGt;
  int rank = tscan[tid];
  float fva[8] = {0, 0, 0, 0, 0, 0, 0, 0};
#pragma unroll
  for (int i = 0; i < 8; ++i) {
    bool inc = sv[i] > tau;
    if (!inc && sv[i] == tau) { inc = (rank < quota); rank++; }
    if (inc) {
      int n = tid * 8 + i;
#pragma unroll
      for (int c = 0; c < 8; ++c) fva[c] += hp[n * 8 + c] * sv[i];
    }
  }
#pragma unroll
  for (int c = 0; c < 8; ++c) atomicAdd(&fvSum[c], fva[c]);
  __syncthreads();

  size_t fo = (size_t)(r * BB + b) * 19;
  if (tid < 8) {
    feats[fo + tid] = chanSum[tid] / (float)NN;        // res = mean over nodes
    feats[fo + 8 + tid] = fvSum[tid] / (float)KK;      // fv  = mean over selected
  }
  if (tid >= 16 && tid < 19) {
    feats[fo + tid] = cen[(size_t)(r * BB + b) * 3 + (tid - 16)];
  }
}

// ---------------- super graph: GAT1 -> LN -> GAT2 -> LN -> pool -> linear ----------------
__global__ __launch_bounds__(256)
void super_kernel(const float* __restrict__ feats,
                  const float* __restrict__ W1, const float* __restrict__ as1,
                  const float* __restrict__ ad1, const float* __restrict__ b1,
                  const float* __restrict__ lnw1, const float* __restrict__ lnb1,
                  const float* __restrict__ W2, const float* __restrict__ as2,
                  const float* __restrict__ ad2, const float* __restrict__ b2,
                  const float* __restrict__ lnw2, const float* __restrict__ lnb2,
                  const float* __restrict__ linw, const float* __restrict__ linb,
                  float* __restrict__ out) {
  __shared__ float sx[NSUP * 19];
  __shared__ float h1[NSUP * 64];
  __shared__ float x1[NSUP * 64];
  __shared__ float es1[NSUP * 4], ed1[NSUP * 4];
  __shared__ float h2[NSUP * 16], x2[NSUP * 16];
  __shared__ float es2[NSUP], ed2[NSUP];
  __shared__ float stat[16];
  const int tid = threadIdx.x;

  // load super_x: node n = b*R + r <- feats[r][b][:]
  for (int i = tid; i < NSUP * 19; i += 256) {
    int n = i / 19, c = i % 19;
    int bb = n / RR, rr = n % RR;
    sx[i] = feats[(size_t)(rr * BB + bb) * 19 + c];
  }
  __syncthreads();
  // h1 = sx @ W1 (no bias pre-attention)
  for (int p = tid; p < NSUP * 64; p += 256) {
    int n = p / 64, j = p % 64;
    float acc = 0.f;
    for (int k2 = 0; k2 < 19; ++k2) acc += sx[n * 19 + k2] * W1[k2 * 64 + j];
    h1[p] = acc;
  }
  __syncthreads();
  for (int p = tid; p < NSUP * 4; p += 256) {
    int n = p / 4, hd = p % 4;
    float a = 0.f, d2 = 0.f;
    for (int o = 0; o < 16; ++o) {
      float hv = h1[n * 64 + hd * 16 + o];
      a += hv * as1[hd * 16 + o];
      d2 += hv * ad1[hd * 16 + o];
    }
    es1[p] = a; ed1[p] = d2;
  }
  __syncthreads();
  // attention: hub (r==0) has self-loop only; others have {hub, self}
  for (int p = tid; p < NSUP * 64; p += 256) {
    int n = p / 64, j = p % 64, hd = j / 16;
    int rr = n % RR;
    float o;
    if (rr == 0) {
      o = h1[p];
    } else {
      int hub = n - rr;
      float eh = es1[hub * 4 + hd] + ed1[n * 4 + hd];
      float esf = es1[n * 4 + hd] + ed1[n * 4 + hd];
      eh = eh > 0.f ? eh : 0.2f * eh;
      esf = esf > 0.f ? esf : 0.2f * esf;
      float m = fmaxf(eh, esf);
      float wh = expf(eh - m), ws2 = expf(esf - m);
      o = (wh * h1[hub * 64 + j] + ws2 * h1[n * 64 + j]) / (wh + ws2);
    }
    float v = o + b1[j];
    x1[p] = v > 0.f ? v : expm1f(v);   // elu
  }
  __syncthreads();
  // graph-LN over (R*64) per patient
  if (tid < BB) {
    double m = 0.0, v2 = 0.0;
    for (int q = 0; q < RR * 64; ++q) {
      float val = x1[tid * RR * 64 + q];
      m += val; v2 += (double)val * val;
    }
    m /= (RR * 64.0); v2 = v2 / (RR * 64.0) - m * m;
    stat[tid] = (float)m;
    stat[8 + tid] = (float)(1.0 / sqrt(v2 + 1e-5));
  }
  __syncthreads();
  for (int p = tid; p < NSUP * 64; p += 256) {
    int n = p / 64, j = p % 64, bb = n / RR;
    x1[p] = (x1[p] - stat[bb]) * stat[8 + bb] * lnw1[j] + lnb1[j];
  }
  __syncthreads();
  // GAT2 (heads=1, oc=16)
  for (int p = tid; p < NSUP * 16; p += 256) {
    int n = p / 16, o = p % 16;
    float acc = 0.f;
    for (int j = 0; j < 64; ++j) acc += x1[n * 64 + j] * W2[j * 16 + o];
    h2[p] = acc;
  }
  __syncthreads();
  for (int n = tid; n < NSUP; n += 256) {
    float a = 0.f, d2 = 0.f;
    for (int o = 0; o < 16; ++o) {
      float hv = h2[n * 16 + o];
      a += hv * as2[o];
      d2 += hv * ad2[o];
    }
    es2[n] = a; ed2[n] = d2;
  }
  __syncthreads();
  for (int p = tid; p < NSUP * 16; p += 256) {
    int n = p / 16, o = p % 16;
    int rr = n % RR;
    float ov;
    if (rr == 0) ov = h2[p];
    else {
      int hub = n - rr;
      float eh = es2[hub] + ed2[n];
      float esf = es2[n] + ed2[n];
      eh = eh > 0.f ? eh : 0.2f * eh;
      esf = esf > 0.f ? esf : 0.2f * esf;
      float m = fmaxf(eh, esf);
      float wh = expf(eh - m), ws2 = expf(esf - m);
      ov = (wh * h2[hub * 16 + o] + ws2 * h2[p]) / (wh + ws2);
    }
    float v = ov + b2[o];
    x2[p] = v > 0.f ? v : expm1f(v);
  }
  __syncthreads();
  if (tid < BB) {
    double m = 0.0, v2 = 0.0;
    for (int q = 0; q < RR * 16; ++q) {
      float val = x2[tid * RR * 16 + q];
      m += val; v2 += (double)val * val;
    }
    m /= (RR * 16.0); v2 = v2 / (RR * 16.0) - m * m;
    stat[tid] = (float)m;
    stat[8 + tid] = (float)(1.0 / sqrt(v2 + 1e-5));
  }
  __syncthreads();
  for (int p = tid; p < NSUP * 16; p += 256) {
    int n = p / 16, o = p % 16, bb = n / RR;
    x2[p] = (x2[p] - stat[bb]) * stat[8 + bb] * lnw2[o] + lnb2[o];
  }
  __syncthreads();
  // pool over ROIs then linear head
  if (tid < BB * 2) {
    int bb = tid / 2, t = tid % 2;
    float acc = linb[t];
    for (int o = 0; o < 16; ++o) {
      float pm = 0.f;
      for (int rr = 0; rr < RR; ++rr) pm += x2[(bb * RR + rr) * 16 + o];
      pm /= (float)RR;
      acc += pm * linw[o * 2 + t];
    }
    out[bb * 2 + t] = acc;
  }
}

extern "C" void kernel_launch(void* const* d_in, const int* in_sizes, int n_in,
                              void* d_out, int out_size, void* d_ws, size_t ws_size,
                              hipStream_t stream) {
  const float* roi_x = (const float*)d_in[0];
  const int* ei = (const int*)d_in[1];
  const float* cen = (const float*)d_in[2];
  const float* gcn_w = (const float*)d_in[3];
  const float* gcn_b = (const float*)d_in[4];
  const float* ln_w = (const float*)d_in[5];
  const float* ln_b = (const float*)d_in[6];
  const float* topk_w = (const float*)d_in[7];
  const float* gat1_w = (const float*)d_in[8];
  const float* as1 = (const float*)d_in[9];
  const float* ad1 = (const float*)d_in[10];
  const float* b1 = (const float*)d_in[11];
  const float* lnw1 = (const float*)d_in[12];
  const float* lnb1 = (const float*)d_in[13];
  const float* W2 = (const float*)d_in[14];
  const float* as2 = (const float*)d_in[15];
  const float* ad2 = (const float*)d_in[16];
  const float* b2 = (const float*)d_in[17];
  const float* lnw2 = (const float*)d_in[18];
  const float* lnb2 = (const float*)d_in[19];
  const float* linw = (const float*)d_in[20];
  const float* linb = (const float*)d_in[21];
  float* out = (float*)d_out;

  // workspace (floats): aggp [nchunks][R*BN*8] | dis [R*BN] | feats [R*B*19]
  // nchunks=2 needs ~45 MB; fall back to 1 chunk (~24 MB) if ws is smaller.
  size_t need2 = ((size_t)2 * RR * BN * 8 + (size_t)RR * BN + (size_t)RR * BB * 19) * sizeof(float);
  int nchunks = (ws_size >= need2) ? 2 : 1;

  float* ws = (float*)d_ws;
  float* aggp = ws;
  float* dis = aggp + (size_t)nchunks * RR * BN * 8;
  float* feats = dis + (size_t)RR * BN;

  deg_dis_kernel<<<RR * BB, 1024, 0, stream>>>(ei, dis);
  agg_kernel2<<<RR * BB * 2 * nchunks, 1024, 0, stream>>>(ei, roi_x, gcn_w, dis, aggp, nchunks);
  roi_kernel<<<RR * BB, 1024, 0, stream>>>(roi_x, gcn_w, gcn_b, ln_w, ln_b,
                                           topk_w, cen, dis, aggp, feats, nchunks);
  super_kernel<<<1, 256, 0, stream>>>(feats, gat1_w, as1, ad1, b1, lnw1, lnb1,
                                      W2, as2, ad2, b2, lnw2, lnb2, linw, linb, out);
}

// Round 6
// 909.947 us; speedup vs baseline: 1.1326x; 1.1326x over previous
//
#include <hip/hip_runtime.h>
#include <hip/hip_bf16.h>
#include <math.h>

// Problem constants (match reference)
#define RR 10
#define BB 8
#define NN 8192
#define HH 8
#define BN 65536            // BB*NN nodes per ROI
#define EE (1u << 20)       // directed edges per ROI = 2*B*EPAIR
#define EPB (EE / BB)       // 131072 directed edges per (ROI,patient), contiguous
#define NPAIR (EPB / 2)     // 65536 undirected pairs per (r,b): edge e and e+NPAIR are the two dirs
#define KK 4096             // TopK ratio 0.5
#define NSUP 80             // B*R super nodes

#define NTL(p) __builtin_nontemporal_load(p)

// ---------------- pass 1: per-(r,b) in-degree via LDS histogram -> dis = rsqrt(deg+1) ----------------
__global__ __launch_bounds__(1024)
void deg_dis_kernel(const int* __restrict__ ei, float* __restrict__ dis) {
  const int r = blockIdx.x / BB;
  const int b = blockIdx.x % BB;
  const int tid = threadIdx.x;
  __shared__ int cnt[NN];                     // 32 KB
  for (int n = tid; n < NN; n += 1024) cnt[n] = 0;
  __syncthreads();
  const int* dstp = ei + ((size_t)r * 2u + 1u) * EE + (size_t)b * EPB;
  for (int e0 = tid; e0 + 3072 < EPB; e0 += 4096) {
    int d0 = NTL(dstp + e0);
    int d1 = NTL(dstp + e0 + 1024);
    int d2 = NTL(dstp + e0 + 2048);
    int d3 = NTL(dstp + e0 + 3072);
    atomicAdd(&cnt[d0 & (NN - 1)], 1);
    atomicAdd(&cnt[d1 & (NN - 1)], 1);
    atomicAdd(&cnt[d2 & (NN - 1)], 1);
    atomicAdd(&cnt[d3 & (NN - 1)], 1);
  }
  __syncthreads();
  float* dp = dis + (size_t)r * BN + (size_t)b * NN;
  for (int n = tid; n < NN; n += 1024) dp[n] = rsqrtf((float)cnt[n] + 1.0f);
}

// ---------------- pass 2: z[n] = (x[n] @ W) * dis[n]  (8 ch, coalesced) ----------------
__global__ __launch_bounds__(1024)
void zprep_kernel(const float* __restrict__ x, const float* __restrict__ gcn_w,
                  const float* __restrict__ dis, float* __restrict__ z) {
  const int r = blockIdx.x / BB;
  const int b = blockIdx.x % BB;
  float w[32];
#pragma unroll
  for (int i = 0; i < 32; ++i) w[i] = gcn_w[r * 32 + i];
  for (int i = threadIdx.x; i < NN; i += 1024) {
    size_t n = (size_t)r * BN + (size_t)b * NN + i;
    float4 xv = ((const float4*)x)[n];
    float ds = dis[n];
    float4 lo, hi;
    lo.x = (xv.x * w[0] + xv.y * w[8]  + xv.z * w[16] + xv.w * w[24]) * ds;
    lo.y = (xv.x * w[1] + xv.y * w[9]  + xv.z * w[17] + xv.w * w[25]) * ds;
    lo.z = (xv.x * w[2] + xv.y * w[10] + xv.z * w[18] + xv.w * w[26]) * ds;
    lo.w = (xv.x * w[3] + xv.y * w[11] + xv.z * w[19] + xv.w * w[27]) * ds;
    hi.x = (xv.x * w[4] + xv.y * w[12] + xv.z * w[20] + xv.w * w[28]) * ds;
    hi.y = (xv.x * w[5] + xv.y * w[13] + xv.z * w[21] + xv.w * w[29]) * ds;
    hi.z = (xv.x * w[6] + xv.y * w[14] + xv.z * w[22] + xv.w * w[30]) * ds;
    hi.w = (xv.x * w[7] + xv.y * w[15] + xv.z * w[23] + xv.w * w[31]) * ds;
    ((float4*)z)[n * 2]     = lo;
    ((float4*)z)[n * 2 + 1] = hi;
  }
}

// ---------------- pass 3: per-(r,b,node-quarter) scatter-add of z[src] into LDS acc[2048][8] ----------------
// agg[d] = dis[d] * sum_s z[s]   (dis[d] applied at writeout -> only ONE gather per visit)
// grid = q*80 + rb  (idx%8 == b -> patient-pinned XCD); 64KB LDS -> 2 blocks/CU
__global__ __launch_bounds__(1024)
void agg_q_kernel(const int* __restrict__ ei,
                  const float* __restrict__ z,
                  const float* __restrict__ dis,
                  float* __restrict__ agg) {
  const int rb = blockIdx.x % 80;
  const int q = blockIdx.x / 80;               // node quarter 0..3
  const int r = rb / BB;
  const int b = rb % BB;
  const int tid = threadIdx.x;

  __shared__ float acc[2048 * 8];              // 64 KB
  for (int i = tid; i < 2048 * 8; i += 1024) acc[i] = 0.f;
  __syncthreads();

  const int* up = ei + (size_t)r * 2u * EE + (size_t)b * EPB;        // pairs: u side
  const int* vp = ei + (size_t)r * 2u * EE + EE + (size_t)b * EPB;   // pairs: v side
  const float4* z4 = (const float4*)z;

  // pair (u,v): dir u->v adds z[u] to acc[v]; dir v->u adds z[v] to acc[u]
#define PROC(U, V)                                                              \
  {                                                                             \
    int lu = (U) & (NN - 1), lv = (V) & (NN - 1);                               \
    if ((lv >> 11) == q) {                                                      \
      const float4* zp = z4 + ((size_t)r * BN + (U)) * 2;                       \
      float4 lo = zp[0], hi = zp[1];                                            \
      int ba = (lv & 2047) * 8, ro = lv & 7;                                    \
      atomicAdd(&acc[ba + ((0 + ro) & 7)], lo.x);                               \
      atomicAdd(&acc[ba + ((1 + ro) & 7)], lo.y);                               \
      atomicAdd(&acc[ba + ((2 + ro) & 7)], lo.z);                               \
      atomicAdd(&acc[ba + ((3 + ro) & 7)], lo.w);                               \
      atomicAdd(&acc[ba + ((4 + ro) & 7)], hi.x);                               \
      atomicAdd(&acc[ba + ((5 + ro) & 7)], hi.y);                               \
      atomicAdd(&acc[ba + ((6 + ro) & 7)], hi.z);                               \
      atomicAdd(&acc[ba + ((7 + ro) & 7)], hi.w);                               \
    }                                                                           \
    if ((lu >> 11) == q) {                                                      \
      const float4* zp = z4 + ((size_t)r * BN + (V)) * 2;                       \
      float4 lo = zp[0], hi = zp[1];                                            \
      int ba = (lu & 2047) * 8, ro = lu & 7;                                    \
      atomicAdd(&acc[ba + ((0 + ro) & 7)], lo.x);                               \
      atomicAdd(&acc[ba + ((1 + ro) & 7)], lo.y);                               \
      atomicAdd(&acc[ba + ((2 + ro) & 7)], lo.z);                               \
      atomicAdd(&acc[ba + ((3 + ro) & 7)], lo.w);                               \
      atomicAdd(&acc[ba + ((4 + ro) & 7)], hi.x);                               \
      atomicAdd(&acc[ba + ((5 + ro) & 7)], hi.y);                               \
      atomicAdd(&acc[ba + ((6 + ro) & 7)], hi.z);                               \
      atomicAdd(&acc[ba + ((7 + ro) & 7)], hi.w);                               \
    }                                                                           \
  }

  for (int e0 = tid; e0 + 3072 < NPAIR; e0 += 4096) {
    int u0 = NTL(up + e0);
    int u1 = NTL(up + e0 + 1024);
    int u2 = NTL(up + e0 + 2048);
    int u3 = NTL(up + e0 + 3072);
    int v0 = NTL(vp + e0);
    int v1 = NTL(vp + e0 + 1024);
    int v2 = NTL(vp + e0 + 2048);
    int v3 = NTL(vp + e0 + 3072);
    PROC(u0, v0)
    PROC(u1, v1)
    PROC(u2, v2)
    PROC(u3, v3)
  }
#undef PROC
  __syncthreads();

  // writeout: nodes [q*2048, q*2048+2048), multiply by dis[d], unswizzle
  const float* disr = dis + (size_t)r * BN + (size_t)b * NN + q * 2048;
  float* ap = agg + ((size_t)r * BN + (size_t)b * NN + (size_t)q * 2048) * 8;
  for (int i = tid; i < 2048; i += 1024) {
    float nd = disr[i];
    int ba = i * 8, ro = i & 7;
    float4 lo, hi;
    lo.x = acc[ba + ((0 + ro) & 7)] * nd;
    lo.y = acc[ba + ((1 + ro) & 7)] * nd;
    lo.z = acc[ba + ((2 + ro) & 7)] * nd;
    lo.w = acc[ba + ((3 + ro) & 7)] * nd;
    hi.x = acc[ba + ((4 + ro) & 7)] * nd;
    hi.y = acc[ba + ((5 + ro) & 7)] * nd;
    hi.z = acc[ba + ((6 + ro) & 7)] * nd;
    hi.w = acc[ba + ((7 + ro) & 7)] * nd;
    ((float4*)ap)[i * 2]     = lo;
    ((float4*)ap)[i * 2 + 1] = hi;
  }
}

// ---------------- per-(ROI,patient): combine + graph-LN + score + radix-select topK + pools ----------------
__global__ __launch_bounds__(1024)
void roi_kernel(const float* __restrict__ z,
                const float* __restrict__ gcn_b,
                const float* __restrict__ ln_w,
                const float* __restrict__ ln_b,
                const float* __restrict__ topk_w,
                const float* __restrict__ cen,
                const float* __restrict__ dis,
                float* __restrict__ hbuf,     // agg in -> hrelu -> hn (in place)
                float* __restrict__ feats) {
  const int r = blockIdx.x / BB;
  const int b = blockIdx.x % BB;
  const int tid = threadIdx.x;

  __shared__ double dred[1024];    // 8 KB reduction
  __shared__ int tscan[1024];      // tie prefix-scan
  __shared__ int hist[256];        // radix histogram
  __shared__ float chanSum[8];
  __shared__ float fvSum[8];
  __shared__ int cntGt;
  __shared__ int selb, kleft;

  if (tid < 8) { chanSum[tid] = 0.f; fvSum[tid] = 0.f; }
  if (tid == 0) cntGt = 0;

  float bg[8], lw[8], lb[8], wt[8];
  float wn2 = 0.f;
#pragma unroll
  for (int c = 0; c < 8; ++c) {
    bg[c] = gcn_b[r * 8 + c];
    lw[c] = ln_w[r * 8 + c];
    lb[c] = ln_b[r * 8 + c];
    wt[c] = topk_w[r * 8 + c];
    wn2 += wt[c] * wt[c];
  }
  const float invn = 1.0f / sqrtf(wn2);

  const float* disp = dis + (size_t)r * BN + (size_t)b * NN;
  const float4* zp = (const float4*)z + ((size_t)r * BN + (size_t)b * NN) * 2;
  float* hp = hbuf + ((size_t)r * BN + (size_t)b * NN) * 8;

  // Pass A: hrelu = relu(agg + z*ds + bias)  [z*ds = h_self/(deg+1) up to rsqrt rounding]
  double s1 = 0.0, s2 = 0.0;
#pragma unroll
  for (int i = 0; i < 8; ++i) {
    int n = tid * 8 + i;
    float ds = disp[n];
    float4 zlo = zp[n * 2], zhi = zp[n * 2 + 1];
    float zs[8] = {zlo.x, zlo.y, zlo.z, zlo.w, zhi.x, zhi.y, zhi.z, zhi.w};
#pragma unroll
    for (int c = 0; c < 8; ++c) {
      float v = hp[n * 8 + c] + zs[c] * ds + bg[c];
      v = fmaxf(v, 0.0f);
      hp[n * 8 + c] = v;
      s1 += v;
      s2 += (double)v * v;
    }
  }
  dred[tid] = s1;
  __syncthreads();
  for (int off = 512; off > 0; off >>= 1) {
    if (tid < off) dred[tid] += dred[tid + off];
    __syncthreads();
  }
  double tot1 = dred[0];
  __syncthreads();
  dred[tid] = s2;
  __syncthreads();
  for (int off = 512; off > 0; off >>= 1) {
    if (tid < off) dred[tid] += dred[tid + off];
    __syncthreads();
  }
  double tot2 = dred[0];
  const double M = (double)NN * HH;
  double mu = tot1 / M;
  double var = tot2 / M - mu * mu;
  float muf = (float)mu;
  float rstd = (float)(1.0 / sqrt(var + 1e-5));

  // Pass B: normalize (in place), per-channel sums (res), scores
  float ch[8] = {0, 0, 0, 0, 0, 0, 0, 0};
  float sv[8];
  unsigned fl[8];
#pragma unroll
  for (int i = 0; i < 8; ++i) {
    int n = tid * 8 + i;
    float pre = 0.f;
#pragma unroll
    for (int c = 0; c < 8; ++c) {
      float v = hp[n * 8 + c];
      float hn = (v - muf) * rstd * lw[c] + lb[c];
      hp[n * 8 + c] = hn;
      ch[c] += hn;
      pre += hn * wt[c];
    }
    float s = tanhf(pre * invn);
    sv[i] = s;
    unsigned u = __float_as_uint(s);
    fl[i] = (u & 0x80000000u) ? ~u : (u | 0x80000000u);  // monotonic flip
  }
#pragma unroll
  for (int c = 0; c < 8; ++c) atomicAdd(&chanSum[c], ch[c]);

  // Radix-select the K-th largest (exact 32-bit value), 4 passes of 8 bits
  unsigned prefix = 0;
  int kneed = KK;
  for (int shift = 24; shift >= 0; shift -= 8) {
    __syncthreads();
    if (tid < 256) hist[tid] = 0;
    __syncthreads();
#pragma unroll
    for (int i = 0; i < 8; ++i) {
      bool m = (shift == 24) || ((fl[i] >> (shift + 8)) == prefix);
      if (m) atomicAdd(&hist[(fl[i] >> shift) & 255], 1);
    }
    __syncthreads();
    if (tid == 0) {
      int kn = kneed, bsel = 0;
      for (int bb2 = 255; bb2 >= 0; --bb2) {
        int c = hist[bb2];
        if (kn - c <= 0) { bsel = bb2; break; }
        kn -= c;
      }
      selb = bsel; kleft = kn;
    }
    __syncthreads();
    prefix = (prefix << 8) | (unsigned)selb;
    kneed = kleft;
  }
  float tau = (prefix & 0x80000000u) ? __uint_as_float(prefix & 0x7fffffffu)
                                     : __uint_as_float(~prefix);

  // count strictly-greater; tie-break lowest-index-first (matches lax.top_k)
  int cg = 0, ct = 0;
#pragma unroll
  for (int i = 0; i < 8; ++i) {
    if (sv[i] > tau) cg++;
    else if (sv[i] == tau) ct++;
  }
  atomicAdd(&cntGt, cg);
  tscan[tid] = ct;
  __syncthreads();
  if (tid == 0) {
    int run = 0;
    for (int t = 0; t < 1024; ++t) { int tmp = tscan[t]; tscan[t] = run; run += tmp; }
  }
  __syncthreads();
  int quota = KK - cntGt;
  int rank = tscan[tid];
  float fva[8] = {0, 0, 0, 0, 0, 0, 0, 0};
#pragma unroll
  for (int i = 0; i < 8; ++i) {
    bool inc = sv[i] > tau;
    if (!inc && sv[i] == tau) { inc = (rank < quota); rank++; }
    if (inc) {
      int n = tid * 8 + i;
#pragma unroll
      for (int c = 0; c < 8; ++c) fva[c] += hp[n * 8 + c] * sv[i];
    }
  }
#pragma unroll
  for (int c = 0; c < 8; ++c) atomicAdd(&fvSum[c], fva[c]);
  __syncthreads();

  size_t fo = (size_t)(r * BB + b) * 19;
  if (tid < 8) {
    feats[fo + tid] = chanSum[tid] / (float)NN;        // res = mean over nodes
    feats[fo + 8 + tid] = fvSum[tid] / (float)KK;      // fv  = mean over selected
  }
  if (tid >= 16 && tid < 19) {
    feats[fo + tid] = cen[(size_t)(r * BB + b) * 3 + (tid - 16)];
  }
}

// ---------------- super graph: GAT1 -> LN -> GAT2 -> LN -> pool -> linear ----------------
__global__ __launch_bounds__(256)
void super_kernel(const float* __restrict__ feats,
                  const float* __restrict__ W1, const float* __restrict__ as1,
                  const float* __restrict__ ad1, const float* __restrict__ b1,
                  const float* __restrict__ lnw1, const float* __restrict__ lnb1,
                  const float* __restrict__ W2, const float* __restrict__ as2,
                  const float* __restrict__ ad2, const float* __restrict__ b2,
                  const float* __restrict__ lnw2, const float* __restrict__ lnb2,
                  const float* __restrict__ linw, const float* __restrict__ linb,
                  float* __restrict__ out) {
  __shared__ float sx[NSUP * 19];
  __shared__ float h1[NSUP * 64];
  __shared__ float x1[NSUP * 64];
  __shared__ float es1[NSUP * 4], ed1[NSUP * 4];
  __shared__ float h2[NSUP * 16], x2[NSUP * 16];
  __shared__ float es2[NSUP], ed2[NSUP];
  __shared__ float stat[16];
  const int tid = threadIdx.x;

  for (int i = tid; i < NSUP * 19; i += 256) {
    int n = i / 19, c = i % 19;
    int bb = n / RR, rr = n % RR;
    sx[i] = feats[(size_t)(rr * BB + bb) * 19 + c];
  }
  __syncthreads();
  for (int p = tid; p < NSUP * 64; p += 256) {
    int n = p / 64, j = p % 64;
    float acc = 0.f;
    for (int k2 = 0; k2 < 19; ++k2) acc += sx[n * 19 + k2] * W1[k2 * 64 + j];
    h1[p] = acc;
  }
  __syncthreads();
  for (int p = tid; p < NSUP * 4; p += 256) {
    int n = p / 4, hd = p % 4;
    float a = 0.f, d2 = 0.f;
    for (int o = 0; o < 16; ++o) {
      float hv = h1[n * 64 + hd * 16 + o];
      a += hv * as1[hd * 16 + o];
      d2 += hv * ad1[hd * 16 + o];
    }
    es1[p] = a; ed1[p] = d2;
  }
  __syncthreads();
  for (int p = tid; p < NSUP * 64; p += 256) {
    int n = p / 64, j = p % 64, hd = j / 16;
    int rr = n % RR;
    float o;
    if (rr == 0) {
      o = h1[p];
    } else {
      int hub = n - rr;
      float eh = es1[hub * 4 + hd] + ed1[n * 4 + hd];
      float esf = es1[n * 4 + hd] + ed1[n * 4 + hd];
      eh = eh > 0.f ? eh : 0.2f * eh;
      esf = esf > 0.f ? esf : 0.2f * esf;
      float m = fmaxf(eh, esf);
      float wh = expf(eh - m), ws2 = expf(esf - m);
      o = (wh * h1[hub * 64 + j] + ws2 * h1[n * 64 + j]) / (wh + ws2);
    }
    float v = o + b1[j];
    x1[p] = v > 0.f ? v : expm1f(v);   // elu
  }
  __syncthreads();
  if (tid < BB) {
    double m = 0.0, v2 = 0.0;
    for (int q = 0; q < RR * 64; ++q) {
      float val = x1[tid * RR * 64 + q];
      m += val; v2 += (double)val * val;
    }
    m /= (RR * 64.0); v2 = v2 / (RR * 64.0) - m * m;
    stat[tid] = (float)m;
    stat[8 + tid] = (float)(1.0 / sqrt(v2 + 1e-5));
  }
  __syncthreads();
  for (int p = tid; p < NSUP * 64; p += 256) {
    int n = p / 64, j = p % 64, bb = n / RR;
    x1[p] = (x1[p] - stat[bb]) * stat[8 + bb] * lnw1[j] + lnb1[j];
  }
  __syncthreads();
  for (int p = tid; p < NSUP * 16; p += 256) {
    int n = p / 16, o = p % 16;
    float acc = 0.f;
    for (int j = 0; j < 64; ++j) acc += x1[n * 64 + j] * W2[j * 16 + o];
    h2[p] = acc;
  }
  __syncthreads();
  for (int n = tid; n < NSUP; n += 256) {
    float a = 0.f, d2 = 0.f;
    for (int o = 0; o < 16; ++o) {
      float hv = h2[n * 16 + o];
      a += hv * as2[o];
      d2 += hv * ad2[o];
    }
    es2[n] = a; ed2[n] = d2;
  }
  __syncthreads();
  for (int p = tid; p < NSUP * 16; p += 256) {
    int n = p / 16, o = p % 16;
    int rr = n % RR;
    float ov;
    if (rr == 0) ov = h2[p];
    else {
      int hub = n - rr;
      float eh = es2[hub] + ed2[n];
      float esf = es2[n] + ed2[n];
      eh = eh > 0.f ? eh : 0.2f * eh;
      esf = esf > 0.f ? esf : 0.2f * esf;
      float m = fmaxf(eh, esf);
      float wh = expf(eh - m), ws2 = expf(esf - m);
      ov = (wh * h2[hub * 16 + o] + ws2 * h2[p]) / (wh + ws2);
    }
    float v = ov + b2[o];
    x2[p] = v > 0.f ? v : expm1f(v);
  }
  __syncthreads();
  if (tid < BB) {
    double m = 0.0, v2 = 0.0;
    for (int q = 0; q < RR * 16; ++q) {
      float val = x2[tid * RR * 16 + q];
      m += val; v2 += (double)val * val;
    }
    m /= (RR * 16.0); v2 = v2 / (RR * 16.0) - m * m;
    stat[tid] = (float)m;
    stat[8 + tid] = (float)(1.0 / sqrt(v2 + 1e-5));
  }
  __syncthreads();
  for (int p = tid; p < NSUP * 16; p += 256) {
    int n = p / 16, o = p % 16, bb = n / RR;
    x2[p] = (x2[p] - stat[bb]) * stat[8 + bb] * lnw2[o] + lnb2[o];
  }
  __syncthreads();
  if (tid < BB * 2) {
    int bb = tid / 2, t = tid % 2;
    float acc = linb[t];
    for (int o = 0; o < 16; ++o) {
      float pm = 0.f;
      for (int rr = 0; rr < RR; ++rr) pm += x2[(bb * RR + rr) * 16 + o];
      pm /= (float)RR;
      acc += pm * linw[o * 2 + t];
    }
    out[bb * 2 + t] = acc;
  }
}

extern "C" void kernel_launch(void* const* d_in, const int* in_sizes, int n_in,
                              void* d_out, int out_size, void* d_ws, size_t ws_size,
                              hipStream_t stream) {
  const float* roi_x = (const float*)d_in[0];
  const int* ei = (const int*)d_in[1];
  const float* cen = (const float*)d_in[2];
  const float* gcn_w = (const float*)d_in[3];
  const float* gcn_b = (const float*)d_in[4];
  const float* ln_w = (const float*)d_in[5];
  const float* ln_b = (const float*)d_in[6];
  const float* topk_w = (const float*)d_in[7];
  const float* gat1_w = (const float*)d_in[8];
  const float* as1 = (const float*)d_in[9];
  const float* ad1 = (const float*)d_in[10];
  const float* b1 = (const float*)d_in[11];
  const float* lnw1 = (const float*)d_in[12];
  const float* lnb1 = (const float*)d_in[13];
  const float* W2 = (const float*)d_in[14];
  const float* as2 = (const float*)d_in[15];
  const float* ad2 = (const float*)d_in[16];
  const float* b2 = (const float*)d_in[17];
  const float* lnw2 = (const float*)d_in[18];
  const float* lnb2 = (const float*)d_in[19];
  const float* linw = (const float*)d_in[20];
  const float* linb = (const float*)d_in[21];
  float* out = (float*)d_out;

  // workspace (floats): agg [R*BN*8] | z [R*BN*8] | dis [R*BN] | feats [R*B*19]  (~45 MB, proven available)
  float* ws = (float*)d_ws;
  float* agg = ws;
  float* z = agg + (size_t)RR * BN * 8;
  float* dis = z + (size_t)RR * BN * 8;
  float* feats = dis + (size_t)RR * BN;

  deg_dis_kernel<<<RR * BB, 1024, 0, stream>>>(ei, dis);
  zprep_kernel<<<RR * BB, 1024, 0, stream>>>(roi_x, gcn_w, dis, z);
  agg_q_kernel<<<RR * BB * 4, 1024, 0, stream>>>(ei, z, dis, agg);
  roi_kernel<<<RR * BB, 1024, 0, stream>>>(z, gcn_b, ln_w, ln_b,
                                           topk_w, cen, dis, agg, feats);
  super_kernel<<<1, 256, 0, stream>>>(feats, gat1_w, as1, ad1, b1, lnw1, lnb1,
                                      W2, as2, ad2, b2, lnw2, lnb2, linw, linb, out);
}

// Round 7
// 449.859 us; speedup vs baseline: 2.2909x; 2.0227x over previous
//
#include <hip/hip_runtime.h>
#include <hip/hip_bf16.h>
#include <math.h>

// Problem constants (match reference)
#define RR 10
#define BB 8
#define NN 8192
#define HH 8
#define BN 65536            // BB*NN nodes per ROI
#define EE (1u << 20)       // directed edges per ROI = 2*B*EPAIR
#define EPB (EE / BB)       // 131072 directed edges per (ROI,patient), contiguous
#define NPAIR (EPB / 2)     // 65536 undirected pairs per (r,b)
#define KK 4096             // TopK ratio 0.5
#define NSUP 80             // B*R super nodes
#define CSRCAP 36864        // slots per (r,b,quarter); mean 32768, +26 sigma slack

#define NTL(p) __builtin_nontemporal_load(p)

// ---------------- build: per-(r,b,q) in-degree count + prefix scan + CSR scatter ----------------
// Writes dis (this quarter's nodes), off/cnt (per-quarter local), csr (ushort local src ids).
// grid = q*80 + rb  (idx%8 == b -> patient-pinned XCD locality)
__global__ __launch_bounds__(1024)
void build_kernel(const int* __restrict__ ei, float* __restrict__ dis,
                  int* __restrict__ offg, int* __restrict__ cntg,
                  unsigned short* __restrict__ csr) {
  const int bid = blockIdx.x;
  const int rb = bid % 80;
  const int q = bid / 80;                 // dst quarter 0..3
  const int r = rb / BB;
  const int b = rb % BB;
  const int tid = threadIdx.x;

  __shared__ int scnt[2048];
  __shared__ int soff[2048];
  __shared__ int scur[2048];
  __shared__ int ps[1024];

  scnt[tid] = 0; scnt[tid + 1024] = 0;
  __syncthreads();

  const int* up = ei + (size_t)r * 2u * EE + (size_t)b * EPB;        // pair u side
  const int* vp = ei + (size_t)r * 2u * EE + EE + (size_t)b * EPB;   // pair v side

  // pass 1: count. dir u->v: dst=v; dir v->u: dst=u.
#define CNT(U, V)                                                   \
  {                                                                 \
    int lv = (V) & (NN - 1);                                        \
    if ((lv >> 11) == q) atomicAdd(&scnt[lv & 2047], 1);            \
    int lu = (U) & (NN - 1);                                        \
    if ((lu >> 11) == q) atomicAdd(&scnt[lu & 2047], 1);            \
  }
  for (int e0 = tid; e0 + 3072 < NPAIR; e0 += 4096) {
    int u0 = NTL(up + e0);
    int u1 = NTL(up + e0 + 1024);
    int u2 = NTL(up + e0 + 2048);
    int u3 = NTL(up + e0 + 3072);
    int v0 = NTL(vp + e0);
    int v1 = NTL(vp + e0 + 1024);
    int v2 = NTL(vp + e0 + 2048);
    int v3 = NTL(vp + e0 + 3072);
    CNT(u0, v0) CNT(u1, v1) CNT(u2, v2) CNT(u3, v3)
  }
#undef CNT
  __syncthreads();

  // exclusive scan over 2048 counts (thread owns elements 2t, 2t+1)
  int a = scnt[2 * tid], b2 = scnt[2 * tid + 1];
  ps[tid] = a + b2;
  __syncthreads();
  for (int s2 = 1; s2 < 1024; s2 <<= 1) {
    int v = 0;
    if (tid >= s2) v = ps[tid - s2];
    __syncthreads();
    ps[tid] += v;
    __syncthreads();
  }
  int ebase = ps[tid] - a - b2;           // exclusive pair base
  soff[2 * tid] = ebase;
  soff[2 * tid + 1] = ebase + a;
  scur[2 * tid] = ebase;
  scur[2 * tid + 1] = ebase + a;

  // write dis / off / cnt for this quarter's 2048 nodes
  size_t nb = (size_t)r * BN + (size_t)b * NN + (size_t)q * 2048;
  dis[nb + 2 * tid] = rsqrtf((float)a + 1.0f);
  dis[nb + 2 * tid + 1] = rsqrtf((float)b2 + 1.0f);
  size_t ob = (size_t)bid * 2048;
  offg[ob + 2 * tid] = ebase;
  offg[ob + 2 * tid + 1] = ebase + a;
  cntg[ob + 2 * tid] = a;
  cntg[ob + 2 * tid + 1] = b2;
  __syncthreads();

  // pass 2: scatter src local ids into csr
  unsigned short* myc = csr + (size_t)bid * CSRCAP;
#define SCAT(U, V)                                                  \
  {                                                                 \
    int lv = (V) & (NN - 1);                                        \
    if ((lv >> 11) == q) {                                          \
      int p = atomicAdd(&scur[lv & 2047], 1);                       \
      myc[p] = (unsigned short)((U) & (NN - 1));                    \
    }                                                               \
    int lu = (U) & (NN - 1);                                        \
    if ((lu >> 11) == q) {                                          \
      int p = atomicAdd(&scur[lu & 2047], 1);                       \
      myc[p] = (unsigned short)((V) & (NN - 1));                    \
    }                                                               \
  }
  for (int e0 = tid; e0 + 3072 < NPAIR; e0 += 4096) {
    int u0 = NTL(up + e0);
    int u1 = NTL(up + e0 + 1024);
    int u2 = NTL(up + e0 + 2048);
    int u3 = NTL(up + e0 + 3072);
    int v0 = NTL(vp + e0);
    int v1 = NTL(vp + e0 + 1024);
    int v2 = NTL(vp + e0 + 2048);
    int v3 = NTL(vp + e0 + 3072);
    SCAT(u0, v0) SCAT(u1, v1) SCAT(u2, v2) SCAT(u3, v3)
  }
#undef SCAT
}

// ---------------- pull: per-(r,b,q) register accumulation over CSR lists ----------------
// P4[d] = dis[d] * sum_{s in N(d)} dis[s] * x[s]   (4 channels; W applied later in roi)
__global__ __launch_bounds__(1024)
void pull_kernel(const float* __restrict__ x, const float* __restrict__ dis,
                 const int* __restrict__ offg, const int* __restrict__ cntg,
                 const unsigned short* __restrict__ csr, float* __restrict__ P4) {
  const int bid = blockIdx.x;
  const int rb = bid % 80;
  const int q = bid / 80;
  const int r = rb / BB;
  const int b = rb % BB;
  const int tid = threadIdx.x;

  const size_t base = (size_t)r * BN + (size_t)b * NN;
  const float4* x4 = (const float4*)x + base;
  const float* dsp = dis + base;
  const unsigned short* myc = csr + (size_t)bid * CSRCAP;
  const size_t ob = (size_t)bid * 2048;

#pragma unroll
  for (int k = 0; k < 2; ++k) {
    int lq = tid + k * 1024;              // index within quarter
    int ln = q * 2048 + lq;               // local node id
    int o = offg[ob + lq];
    int c = cntg[ob + lq];
    float sx = 0.f, sy = 0.f, sz = 0.f, sw = 0.f;
    int j = 0;
    for (; j + 1 < c; j += 2) {           // 2-edge ILP
      int s0 = myc[o + j];
      int s1 = myc[o + j + 1];
      float d0 = dsp[s0];
      float d1 = dsp[s1];
      float4 a0 = x4[s0];
      float4 a1 = x4[s1];
      sx += a0.x * d0 + a1.x * d1;
      sy += a0.y * d0 + a1.y * d1;
      sz += a0.z * d0 + a1.z * d1;
      sw += a0.w * d0 + a1.w * d1;
    }
    if (j < c) {
      int s0 = myc[o + j];
      float d0 = dsp[s0];
      float4 a0 = x4[s0];
      sx += a0.x * d0; sy += a0.y * d0; sz += a0.z * d0; sw += a0.w * d0;
    }
    float dd = dsp[ln];
    ((float4*)P4)[base + ln] = make_float4(sx * dd, sy * dd, sz * dd, sw * dd);
  }
}

// ---------------- per-(ROI,patient): combine + graph-LN + score + radix-select topK + pools ----------------
// hn is recomputed per pass from (P4 + x*dis^2)@W -- no big hn buffer needed.
__global__ __launch_bounds__(1024)
void roi_kernel(const float* __restrict__ x,
                const float* __restrict__ gcn_w,
                const float* __restrict__ gcn_b,
                const float* __restrict__ ln_w,
                const float* __restrict__ ln_b,
                const float* __restrict__ topk_w,
                const float* __restrict__ cen,
                const float* __restrict__ dis,
                const float* __restrict__ P4,
                float* __restrict__ feats) {
  const int r = blockIdx.x / BB;
  const int b = blockIdx.x % BB;
  const int tid = threadIdx.x;

  __shared__ double dred[1024];
  __shared__ int tscan[1024];
  __shared__ int hist[256];
  __shared__ float chanSum[8];
  __shared__ float fvSum[8];
  __shared__ int cntGt;
  __shared__ int selb, kleft;

  if (tid < 8) { chanSum[tid] = 0.f; fvSum[tid] = 0.f; }
  if (tid == 0) cntGt = 0;

  float w[32], bg[8], lw[8], lb[8], wt[8];
#pragma unroll
  for (int i = 0; i < 32; ++i) w[i] = gcn_w[r * 32 + i];
  float wn2 = 0.f;
#pragma unroll
  for (int c = 0; c < 8; ++c) {
    bg[c] = gcn_b[r * 8 + c];
    lw[c] = ln_w[r * 8 + c];
    lb[c] = ln_b[r * 8 + c];
    wt[c] = topk_w[r * 8 + c];
    wn2 += wt[c] * wt[c];
  }
  const float invn = 1.0f / sqrtf(wn2);

  const size_t base = (size_t)r * BN + (size_t)b * NN;
  const float4* x4 = (const float4*)x + base;
  const float4* p4 = (const float4*)P4 + base;
  const float* disp = dis + base;

  // v4[n] = P4[n] + x[n]*dis[n]^2 ; hrelu[c] = relu(v4 @ W[:,c] + bg[c])
#define V4(n, out)                                          \
  {                                                         \
    float ds = disp[n];                                     \
    float4 pv = p4[n];                                      \
    float4 xv = x4[n];                                      \
    float i2 = ds * ds;                                     \
    out.x = pv.x + xv.x * i2;                               \
    out.y = pv.y + xv.y * i2;                               \
    out.z = pv.z + xv.z * i2;                               \
    out.w = pv.w + xv.w * i2;                               \
  }
#define HREL(v4v, c) fmaxf(v4v.x * w[c] + v4v.y * w[8 + c] + v4v.z * w[16 + c] + v4v.w * w[24 + c] + bg[c], 0.0f)

  // Pass A: fp64 LN stats over hrelu
  double s1 = 0.0, s2 = 0.0;
#pragma unroll
  for (int i = 0; i < 8; ++i) {
    int n = tid * 8 + i;
    float4 vv; V4(n, vv)
#pragma unroll
    for (int c = 0; c < 8; ++c) {
      float v = HREL(vv, c);
      s1 += v;
      s2 += (double)v * v;
    }
  }
  dred[tid] = s1;
  __syncthreads();
  for (int off = 512; off > 0; off >>= 1) {
    if (tid < off) dred[tid] += dred[tid + off];
    __syncthreads();
  }
  double tot1 = dred[0];
  __syncthreads();
  dred[tid] = s2;
  __syncthreads();
  for (int off = 512; off > 0; off >>= 1) {
    if (tid < off) dred[tid] += dred[tid + off];
    __syncthreads();
  }
  double tot2 = dred[0];
  const double M = (double)NN * HH;
  double mu = tot1 / M;
  double var = tot2 / M - mu * mu;
  float muf = (float)mu;
  float rstd = (float)(1.0 / sqrt(var + 1e-5));

  // Pass B: hn = (hrelu - mu)*rstd*lw + lb ; per-channel sums + scores
  float ch[8] = {0, 0, 0, 0, 0, 0, 0, 0};
  float sv[8];
  unsigned fl[8];
#pragma unroll
  for (int i = 0; i < 8; ++i) {
    int n = tid * 8 + i;
    float4 vv; V4(n, vv)
    float pre = 0.f;
#pragma unroll
    for (int c = 0; c < 8; ++c) {
      float v = HREL(vv, c);
      float hn = (v - muf) * rstd * lw[c] + lb[c];
      ch[c] += hn;
      pre += hn * wt[c];
    }
    float s = tanhf(pre * invn);
    sv[i] = s;
    unsigned u = __float_as_uint(s);
    fl[i] = (u & 0x80000000u) ? ~u : (u | 0x80000000u);  // monotonic flip
  }
#pragma unroll
  for (int c = 0; c < 8; ++c) atomicAdd(&chanSum[c], ch[c]);

  // Radix-select the K-th largest (exact 32-bit value), 4 passes of 8 bits
  unsigned prefix = 0;
  int kneed = KK;
  for (int shift = 24; shift >= 0; shift -= 8) {
    __syncthreads();
    if (tid < 256) hist[tid] = 0;
    __syncthreads();
#pragma unroll
    for (int i = 0; i < 8; ++i) {
      bool m = (shift == 24) || ((fl[i] >> (shift + 8)) == prefix);
      if (m) atomicAdd(&hist[(fl[i] >> shift) & 255], 1);
    }
    __syncthreads();
    if (tid == 0) {
      int kn = kneed, bsel = 0;
      for (int bb2 = 255; bb2 >= 0; --bb2) {
        int c = hist[bb2];
        if (kn - c <= 0) { bsel = bb2; break; }
        kn -= c;
      }
      selb = bsel; kleft = kn;
    }
    __syncthreads();
    prefix = (prefix << 8) | (unsigned)selb;
    kneed = kleft;
  }
  float tau = (prefix & 0x80000000u) ? __uint_as_float(prefix & 0x7fffffffu)
                                     : __uint_as_float(~prefix);

  // count strictly-greater; tie-break lowest-index-first (matches lax.top_k)
  int cg = 0, ct = 0;
#pragma unroll
  for (int i = 0; i < 8; ++i) {
    if (sv[i] > tau) cg++;
    else if (sv[i] == tau) ct++;
  }
  atomicAdd(&cntGt, cg);
  tscan[tid] = ct;
  __syncthreads();
  if (tid == 0) {
    int run = 0;
    for (int t = 0; t < 1024; ++t) { int tmp = tscan[t]; tscan[t] = run; run += tmp; }
  }
  __syncthreads();
  int quota = KK - cntGt;
  int rank = tscan[tid];
  float fva[8] = {0, 0, 0, 0, 0, 0, 0, 0};
#pragma unroll
  for (int i = 0; i < 8; ++i) {
    bool inc = sv[i] > tau;
    if (!inc && sv[i] == tau) { inc = (rank < quota); rank++; }
    if (inc) {
      int n = tid * 8 + i;
      float4 vv; V4(n, vv)
#pragma unroll
      for (int c = 0; c < 8; ++c) {
        float v = HREL(vv, c);
        float hn = (v - muf) * rstd * lw[c] + lb[c];
        fva[c] += hn * sv[i];
      }
    }
  }
#undef V4
#undef HREL
#pragma unroll
  for (int c = 0; c < 8; ++c) atomicAdd(&fvSum[c], fva[c]);
  __syncthreads();

  size_t fo = (size_t)(r * BB + b) * 19;
  if (tid < 8) {
    feats[fo + tid] = chanSum[tid] / (float)NN;        // res
    feats[fo + 8 + tid] = fvSum[tid] / (float)KK;      // fv
  }
  if (tid >= 16 && tid < 19) {
    feats[fo + tid] = cen[(size_t)(r * BB + b) * 3 + (tid - 16)];
  }
}

// ---------------- super graph: GAT1 -> LN -> GAT2 -> LN -> pool -> linear ----------------
__global__ __launch_bounds__(256)
void super_kernel(const float* __restrict__ feats,
                  const float* __restrict__ W1, const float* __restrict__ as1,
                  const float* __restrict__ ad1, const float* __restrict__ b1,
                  const float* __restrict__ lnw1, const float* __restrict__ lnb1,
                  const float* __restrict__ W2, const float* __restrict__ as2,
                  const float* __restrict__ ad2, const float* __restrict__ b2,
                  const float* __restrict__ lnw2, const float* __restrict__ lnb2,
                  const float* __restrict__ linw, const float* __restrict__ linb,
                  float* __restrict__ out) {
  __shared__ float sx[NSUP * 19];
  __shared__ float h1[NSUP * 64];
  __shared__ float x1[NSUP * 64];
  __shared__ float es1[NSUP * 4], ed1[NSUP * 4];
  __shared__ float h2[NSUP * 16], x2[NSUP * 16];
  __shared__ float es2[NSUP], ed2[NSUP];
  __shared__ float stat[16];
  const int tid = threadIdx.x;

  for (int i = tid; i < NSUP * 19; i += 256) {
    int n = i / 19, c = i % 19;
    int bb = n / RR, rr = n % RR;
    sx[i] = feats[(size_t)(rr * BB + bb) * 19 + c];
  }
  __syncthreads();
  for (int p = tid; p < NSUP * 64; p += 256) {
    int n = p / 64, j = p % 64;
    float acc = 0.f;
    for (int k2 = 0; k2 < 19; ++k2) acc += sx[n * 19 + k2] * W1[k2 * 64 + j];
    h1[p] = acc;
  }
  __syncthreads();
  for (int p = tid; p < NSUP * 4; p += 256) {
    int n = p / 4, hd = p % 4;
    float a = 0.f, d2 = 0.f;
    for (int o = 0; o < 16; ++o) {
      float hv = h1[n * 64 + hd * 16 + o];
      a += hv * as1[hd * 16 + o];
      d2 += hv * ad1[hd * 16 + o];
    }
    es1[p] = a; ed1[p] = d2;
  }
  __syncthreads();
  for (int p = tid; p < NSUP * 64; p += 256) {
    int n = p / 64, j = p % 64, hd = j / 16;
    int rr = n % RR;
    float o;
    if (rr == 0) {
      o = h1[p];
    } else {
      int hub = n - rr;
      float eh = es1[hub * 4 + hd] + ed1[n * 4 + hd];
      float esf = es1[n * 4 + hd] + ed1[n * 4 + hd];
      eh = eh > 0.f ? eh : 0.2f * eh;
      esf = esf > 0.f ? esf : 0.2f * esf;
      float m = fmaxf(eh, esf);
      float wh = expf(eh - m), ws2 = expf(esf - m);
      o = (wh * h1[hub * 64 + j] + ws2 * h1[n * 64 + j]) / (wh + ws2);
    }
    float v = o + b1[j];
    x1[p] = v > 0.f ? v : expm1f(v);   // elu
  }
  __syncthreads();
  if (tid < BB) {
    double m = 0.0, v2 = 0.0;
    for (int q = 0; q < RR * 64; ++q) {
      float val = x1[tid * RR * 64 + q];
      m += val; v2 += (double)val * val;
    }
    m /= (RR * 64.0); v2 = v2 / (RR * 64.0) - m * m;
    stat[tid] = (float)m;
    stat[8 + tid] = (float)(1.0 / sqrt(v2 + 1e-5));
  }
  __syncthreads();
  for (int p = tid; p < NSUP * 64; p += 256) {
    int n = p / 64, j = p % 64, bb = n / RR;
    x1[p] = (x1[p] - stat[bb]) * stat[8 + bb] * lnw1[j] + lnb1[j];
  }
  __syncthreads();
  for (int p = tid; p < NSUP * 16; p += 256) {
    int n = p / 16, o = p % 16;
    float acc = 0.f;
    for (int j = 0; j < 64; ++j) acc += x1[n * 64 + j] * W2[j * 16 + o];
    h2[p] = acc;
  }
  __syncthreads();
  for (int n = tid; n < NSUP; n += 256) {
    float a = 0.f, d2 = 0.f;
    for (int o = 0; o < 16; ++o) {
      float hv = h2[n * 16 + o];
      a += hv * as2[o];
      d2 += hv * ad2[o];
    }
    es2[n] = a; ed2[n] = d2;
  }
  __syncthreads();
  for (int p = tid; p < NSUP * 16; p += 256) {
    int n = p / 16, o = p % 16;
    int rr = n % RR;
    float ov;
    if (rr == 0) ov = h2[p];
    else {
      int hub = n - rr;
      float eh = es2[hub] + ed2[n];
      float esf = es2[n] + ed2[n];
      eh = eh > 0.f ? eh : 0.2f * eh;
      esf = esf > 0.f ? esf : 0.2f * esf;
      float m = fmaxf(eh, esf);
      float wh = expf(eh - m), ws2 = expf(esf - m);
      ov = (wh * h2[hub * 16 + o] + ws2 * h2[p]) / (wh + ws2);
    }
    float v = ov + b2[o];
    x2[p] = v > 0.f ? v : expm1f(v);
  }
  __syncthreads();
  if (tid < BB) {
    double m = 0.0, v2 = 0.0;
    for (int q = 0; q < RR * 16; ++q) {
      float val = x2[tid * RR * 16 + q];
      m += val; v2 += (double)val * val;
    }
    m /= (RR * 16.0); v2 = v2 / (RR * 16.0) - m * m;
    stat[tid] = (float)m;
    stat[8 + tid] = (float)(1.0 / sqrt(v2 + 1e-5));
  }
  __syncthreads();
  for (int p = tid; p < NSUP * 16; p += 256) {
    int n = p / 16, o = p % 16, bb = n / RR;
    x2[p] = (x2[p] - stat[bb]) * stat[8 + bb] * lnw2[o] + lnb2[o];
  }
  __syncthreads();
  if (tid < BB * 2) {
    int bb = tid / 2, t = tid % 2;
    float acc = linb[t];
    for (int o = 0; o < 16; ++o) {
      float pm = 0.f;
      for (int rr = 0; rr < RR; ++rr) pm += x2[(bb * RR + rr) * 16 + o];
      pm /= (float)RR;
      acc += pm * linw[o * 2 + t];
    }
    out[bb * 2 + t] = acc;
  }
}

extern "C" void kernel_launch(void* const* d_in, const int* in_sizes, int n_in,
                              void* d_out, int out_size, void* d_ws, size_t ws_size,
                              hipStream_t stream) {
  const float* roi_x = (const float*)d_in[0];
  const int* ei = (const int*)d_in[1];
  const float* cen = (const float*)d_in[2];
  const float* gcn_w = (const float*)d_in[3];
  const float* gcn_b = (const float*)d_in[4];
  const float* ln_w = (const float*)d_in[5];
  const float* ln_b = (const float*)d_in[6];
  const float* topk_w = (const float*)d_in[7];
  const float* gat1_w = (const float*)d_in[8];
  const float* as1 = (const float*)d_in[9];
  const float* ad1 = (const float*)d_in[10];
  const float* b1 = (const float*)d_in[11];
  const float* lnw1 = (const float*)d_in[12];
  const float* lnb1 = (const float*)d_in[13];
  const float* W2 = (const float*)d_in[14];
  const float* as2 = (const float*)d_in[15];
  const float* ad2 = (const float*)d_in[16];
  const float* b2 = (const float*)d_in[17];
  const float* lnw2 = (const float*)d_in[18];
  const float* lnb2 = (const float*)d_in[19];
  const float* linw = (const float*)d_in[20];
  const float* linb = (const float*)d_in[21];
  float* out = (float*)d_out;

  // ws layout: P4 [R*BN*4 f] | dis [R*BN f] | off [320*2048 i] | cnt [320*2048 i]
  //          | feats [R*B*19 f] | csr [320*CSRCAP ushort]   total ~42 MB (ws >= 45 MB proven)
  float* ws = (float*)d_ws;
  float* P4 = ws;
  float* dis = P4 + (size_t)RR * BN * 4;
  int* offg = (int*)(dis + (size_t)RR * BN);
  int* cntg = offg + (size_t)320 * 2048;
  float* feats = (float*)(cntg + (size_t)320 * 2048);
  unsigned short* csr = (unsigned short*)(feats + (size_t)RR * BB * 19);

  build_kernel<<<320, 1024, 0, stream>>>(ei, dis, offg, cntg, csr);
  pull_kernel<<<320, 1024, 0, stream>>>(roi_x, dis, offg, cntg, csr, P4);
  roi_kernel<<<RR * BB, 1024, 0, stream>>>(roi_x, gcn_w, gcn_b, ln_w, ln_b,
                                           topk_w, cen, dis, P4, feats);
  super_kernel<<<1, 256, 0, stream>>>(feats, gat1_w, as1, ad1, b1, lnw1, lnb1,
                                      W2, as2, ad2, b2, lnw2, lnb2, linw, linb, out);
}